// Round 7
// baseline (432.302 us; speedup 1.0000x reference)
//
#include <hip/hip_runtime.h>

// B=128, x1/x2/x3 (B,2048,7,7) f32, W (14,2048), b (14,)
// softmax over singleton axis == 1.0 exactly  =>  h = 2*x1 + x2  (x3 unused!)
// feats[b,n] = mean_c(2*x1 + x2) ; logits = feats @ W^T + b
// Output layout: logits (128*14) then feats (128*2048), f32 flat.
//
// Round-7: round 6's cooperative launch silently failed under graph capture.
// Same single-dispatch goal via last-block-done pattern instead: every block
// writes fc partials, __threadfence + atomicAdd(counter); the 4096th block
// reduces all logits. Counter zeroed per call with hipMemsetAsync (graph-
// legal). Keeps round-5's proven pipeline: coalesced float4 -> LDS -> 4-lane
// row reduce. Adds coalesced float4 feats writes. No same-line data atomics
// (round 2: those serialize ~47cy/op); ONE counter atomic per block spread
// over the kernel's lifetime is harmless.

#define NROWS (128 * 2048)
#define FC_B 128
#define FC_N 2048
#define FC_J 14
#define RPB 64                          // rows per block
#define TILE_F (RPB * 49)               // 3136 floats
#define TILE_V (TILE_F / 4)             // 784 float4
#define NBLK (NROWS / RPB)              // 4096
#define BPB (FC_N / RPB)                // 32 blocks per batch row
#define PART_BYTES (NBLK * FC_J * 4)    // 229376

__global__ __launch_bounds__(256) void fused_kernel(
    const float* __restrict__ x1, const float* __restrict__ x2,
    const float* __restrict__ W, const float* __restrict__ bias,
    float* __restrict__ feats, float* __restrict__ logits,
    float* __restrict__ part, unsigned int* __restrict__ counter)
{
    const int tid = threadIdx.x;
    __shared__ float sm[TILE_F];
    __shared__ float sf[RPB];
    __shared__ int is_last;

    // ---- Phase 1: coalesced float4 stream -> LDS (combined 2*x1+x2) ----
    const float4* q1 = (const float4*)x1 + (size_t)blockIdx.x * TILE_V;
    const float4* q2 = (const float4*)x2 + (size_t)blockIdx.x * TILE_V;
    float4* smv = (float4*)sm;

    #pragma unroll
    for (int k = 0; k < 3; ++k) {            // 3*256 = 768 of 784
        const int i = k * 256 + tid;
        const float4 a = q1[i];
        const float4 c = q2[i];
        float4 v;
        v.x = 2.0f * a.x + c.x;
        v.y = 2.0f * a.y + c.y;
        v.z = 2.0f * a.z + c.z;
        v.w = 2.0f * a.w + c.w;
        smv[i] = v;
    }
    if (tid < TILE_V - 768) {                // tail: 16 float4
        const int i = 768 + tid;
        const float4 a = q1[i];
        const float4 c = q2[i];
        float4 v;
        v.x = 2.0f * a.x + c.x;
        v.y = 2.0f * a.y + c.y;
        v.z = 2.0f * a.z + c.z;
        v.w = 2.0f * a.w + c.w;
        smv[i] = v;
    }
    __syncthreads();

    // ---- Phase 2: row sums. 4 threads/row, stride-4 over 48 + tail ----
    const int row = tid >> 2;                // 0..63
    const int t = tid & 3;
    const float* rp = sm + row * 49;
    float v = 0.0f;
    #pragma unroll
    for (int k = 0; k < 12; ++k)
        v += rp[t + 4 * k];
    if (t == 0) v += rp[48];
    v += __shfl_xor(v, 1, 4);
    v += __shfl_xor(v, 2, 4);
    if (t == 0) sf[row] = v * (1.0f / 49.0f);
    __syncthreads();

    // ---- Phase 2b: coalesced feats write (16 float4 = 64 rows) ----
    if (tid < RPB / 4)
        ((float4*)(feats + (size_t)blockIdx.x * RPB))[tid] = ((float4*)sf)[tid];

    // ---- Phase 3: fc partials -> part[b][j][blkin] (reader-contiguous) ----
    const int bb = blockIdx.x / BPB;
    const int blkin = blockIdx.x % BPB;
    if (tid < FC_J) {
        const float* wrow = W + tid * FC_N + blkin * RPB;  // W L2-resident
        float acc = 0.0f;
        #pragma unroll
        for (int k = 0; k < RPB; ++k)
            acc += sf[k] * wrow[k];
        part[((size_t)bb * FC_J + tid) * BPB + blkin] = acc;
    }

    // ---- Phase 4: last block reduces logits ----
    __threadfence();                          // release partials (device scope)
    if (tid == 0)
        is_last = (atomicAdd(counter, 1u) == NBLK - 1);
    __syncthreads();
    if (!is_last) return;

    __threadfence();                          // acquire all partials
    for (int idx = tid; idx < FC_B * FC_J; idx += 256) {
        const float* pp = part + (size_t)idx * BPB;   // 32 contiguous floats
        float s = 0.0f;
        #pragma unroll
        for (int k = 0; k < BPB; k += 4) {
            const float4 p = *(const float4*)(pp + k);
            s += p.x + p.y + p.z + p.w;
        }
        logits[idx] = s + bias[idx % FC_J];
    }
}

extern "C" void kernel_launch(void* const* d_in, const int* in_sizes, int n_in,
                              void* d_out, int out_size, void* d_ws, size_t ws_size,
                              hipStream_t stream) {
    const float* x1 = (const float*)d_in[0];
    const float* x2 = (const float*)d_in[1];
    // d_in[2] = x3 — provably unused (softmax over singleton axis == 1)
    const float* W = (const float*)d_in[3];
    const float* bias = (const float*)d_in[4];

    float* out = (float*)d_out;
    float* logits = out;                 // 128*14
    float* feats = out + FC_B * FC_J;    // 128*2048

    float* part = (float*)d_ws;                                  // 229376 B
    unsigned int* counter = (unsigned int*)((char*)d_ws + PART_BYTES);

    hipMemsetAsync(counter, 0, sizeof(unsigned int), stream);    // graph-legal
    fused_kernel<<<NBLK, 256, 0, stream>>>(x1, x2, W, bias,
                                           feats, logits, part, counter);
}

// Round 8
// 24.335 us; speedup vs baseline: 17.7647x; 17.7647x over previous
//
#include <hip/hip_runtime.h>

// B=128, x1/x2/x3 (B,2048,7,7) f32, W (14,2048), b (14,)
// softmax over singleton axis == 1.0 exactly  =>  h = 2*x1 + x2  (x3 unused!)
// feats[b,n] = mean_c(2*x1 + x2) ; logits = feats @ W^T + b
// Output layout: logits (128*14) then feats (128*2048), f32 flat.
//
// Round-8: revert to round-5 two-dispatch structure (round 6 coop-launch
// failed under graph capture; round 7's per-block __threadfence caused L2
// writeback storms -> 585us). New: stage x1/x2 tiles RAW into LDS via
// __builtin_amdgcn_global_load_lds width=16 (async DMA, no VGPR round-trip,
// deeper outstanding-load queue). Phase 2 combines 2*s1+s2 during the row
// reduce. No atomics, no fences.

#define NROWS (128 * 2048)
#define FC_B 128
#define FC_N 2048
#define FC_J 14
#define RPB 64                          // rows per block
#define TILE_F (RPB * 49)               // 3136 floats
#define TILE_V (TILE_F / 4)             // 784 float4
#define NBLK (NROWS / RPB)              // 4096
#define BPB (FC_N / RPB)                // 32 blocks per batch row

__global__ __launch_bounds__(256) void fused_kernel(
    const float* __restrict__ x1, const float* __restrict__ x2,
    const float* __restrict__ W,
    float* __restrict__ feats, float* __restrict__ part)
{
    const int tid = threadIdx.x;
    const int wid = tid >> 6;            // wave 0..3
    const int lane = tid & 63;
    __shared__ float sm1[TILE_F];
    __shared__ float sm2[TILE_F];
    __shared__ float sf[RPB];

    const float4* q1 = (const float4*)x1 + (size_t)blockIdx.x * TILE_V;
    const float4* q2 = (const float4*)x2 + (size_t)blockIdx.x * TILE_V;

    // ---- Phase 1: async global->LDS DMA, 16B/lane, wave-uniform LDS base.
    // 3 rounds x 256 threads covers 768 of 784 float4 per input.
    #pragma unroll
    for (int k = 0; k < 3; ++k) {
        const int base = k * 256 + wid * 64;   // float4 idx, uniform per wave
        __builtin_amdgcn_global_load_lds(
            (const __attribute__((address_space(1))) uint32_t*)(q1 + base + lane),
            (__attribute__((address_space(3))) uint32_t*)((float4*)sm1 + base),
            16, 0, 0);
        __builtin_amdgcn_global_load_lds(
            (const __attribute__((address_space(1))) uint32_t*)(q2 + base + lane),
            (__attribute__((address_space(3))) uint32_t*)((float4*)sm2 + base),
            16, 0, 0);
    }
    // tail: 16 float4 per input via plain ld/st (avoid partial-wave DMA)
    if (tid < 16) {
        ((float4*)sm1)[768 + tid] = q1[768 + tid];
    } else if (tid >= 64 && tid < 80) {
        ((float4*)sm2)[768 + (tid - 64)] = q2[768 + (tid - 64)];
    }
    __syncthreads();   // drains vmcnt (incl. global_load_lds) + lgkmcnt

    // ---- Phase 2: row sums. 4 threads/row, stride-4 over 48 + tail ----
    const int row = tid >> 2;                // 0..63
    const int t = tid & 3;
    const float* r1 = sm1 + row * 49;
    const float* r2 = sm2 + row * 49;
    float s1 = 0.0f, s2 = 0.0f;
    #pragma unroll
    for (int k = 0; k < 12; ++k) {
        s1 += r1[t + 4 * k];
        s2 += r2[t + 4 * k];
    }
    if (t == 0) { s1 += r1[48]; s2 += r2[48]; }
    float v = 2.0f * s1 + s2;
    v += __shfl_xor(v, 1, 4);
    v += __shfl_xor(v, 2, 4);
    if (t == 0) sf[row] = v * (1.0f / 49.0f);
    __syncthreads();

    // ---- Phase 2b: coalesced feats write (16 x float4 = 64 rows) ----
    if (tid < RPB / 4)
        ((float4*)(feats + (size_t)blockIdx.x * RPB))[tid] = ((float4*)sf)[tid];

    // ---- Phase 3: fc partials -> part[b][j][blkin] (reader-contiguous) ----
    const int bb = blockIdx.x / BPB;
    const int blkin = blockIdx.x % BPB;
    if (tid < FC_J) {
        const float* wrow = W + tid * FC_N + blkin * RPB;  // W is L2-resident
        float acc = 0.0f;
        #pragma unroll
        for (int k = 0; k < RPB; ++k)
            acc += sf[k] * wrow[k];
        part[((size_t)bb * FC_J + tid) * BPB + blkin] = acc;
    }
}

__global__ __launch_bounds__(256) void gather_kernel(const float* __restrict__ part,
                                                     const float* __restrict__ bias,
                                                     float* __restrict__ logits) {
    const int idx = blockIdx.x * 256 + threadIdx.x;
    if (idx >= FC_B * FC_J) return;
    const float* pp = part + (size_t)idx * BPB;   // 32 contiguous floats
    float s = 0.0f;
    #pragma unroll
    for (int k = 0; k < BPB; k += 4) {
        const float4 p = *(const float4*)(pp + k);
        s += p.x + p.y + p.z + p.w;
    }
    logits[idx] = s + bias[idx % FC_J];
}

extern "C" void kernel_launch(void* const* d_in, const int* in_sizes, int n_in,
                              void* d_out, int out_size, void* d_ws, size_t ws_size,
                              hipStream_t stream) {
    const float* x1 = (const float*)d_in[0];
    const float* x2 = (const float*)d_in[1];
    // d_in[2] = x3 — provably unused (softmax over singleton axis == 1)
    const float* W = (const float*)d_in[3];
    const float* bias = (const float*)d_in[4];

    float* out = (float*)d_out;
    float* logits = out;                 // 128*14
    float* feats = out + FC_B * FC_J;    // 128*2048

    float* part = (float*)d_ws;          // 128*14*32*4 = 229 KB scratch

    fused_kernel<<<NBLK, 256, 0, stream>>>(x1, x2, W, feats, part);
    gather_kernel<<<(FC_B * FC_J + 255) / 256, 256, 0, stream>>>(part, bias, logits);
}